// Round 1
// baseline (212.309 us; speedup 1.0000x reference)
//
#include <hip/hip_runtime.h>
#include <hip/hip_bf16.h>
#include <math.h>

// Problem constants (B=2, H=12, S=2048, D=64, hash_code_len=8)
#define NB 2
#define NH 12
#define NS 2048
#define ND 64
#define NBH (NB * NH)
#define LDK 72          // padded LDS row length in bf16 elems (144 B, 16B-aligned)

typedef __attribute__((ext_vector_type(8))) short short8;   // 8 bf16 = 4 VGPRs (MFMA A/B frag)
typedef __attribute__((ext_vector_type(4))) float floatx4;  // MFMA C/D frag

__device__ __forceinline__ unsigned short f32_to_bf16(float f) {
  unsigned int u = __float_as_uint(f);
  u += 0x7fffu + ((u >> 16) & 1u);   // round-to-nearest-even
  return (unsigned short)(u >> 16);
}

// ---------------------------------------------------------------------------
// Prep 1: l2-normalize Q and K rows (D=64) and cast to bf16.
// One wave per row; 4 waves / block. Rows: [0, NBH*NS) -> Q, then K.
// ---------------------------------------------------------------------------
__global__ __launch_bounds__(256) void prep_qk(
    const float* __restrict__ Q, const float* __restrict__ K,
    unsigned short* __restrict__ qn, unsigned short* __restrict__ kn) {
  int wave = blockIdx.x * 4 + (threadIdx.x >> 6);
  int lane = threadIdx.x & 63;
  const int rows = NBH * NS;
  const float* src;
  unsigned short* dst;
  int row;
  if (wave < rows) { src = Q; dst = qn; row = wave; }
  else             { src = K; dst = kn; row = wave - rows; }
  float x = src[(size_t)row * ND + lane];
  float ss = x * x;
  #pragma unroll
  for (int m = 32; m >= 1; m >>= 1) ss += __shfl_xor(ss, m, 64);
  float rn = 1.0f / fmaxf(sqrtf(ss), 1e-12f);
  dst[(size_t)row * ND + lane] = f32_to_bf16(x * rn);
}

// ---------------------------------------------------------------------------
// Prep 2: V [bh][t][d] fp32 -> Vt [bh][d][t] bf16 (transposed, so it reads as
// a contiguous K-major B-operand for the W*V MFMA).
// One block per (bh, 64-t tile).
// ---------------------------------------------------------------------------
__global__ __launch_bounds__(256) void prep_v(
    const float* __restrict__ V, unsigned short* __restrict__ Vt) {
  int bh = blockIdx.x >> 5;          // NS/64 = 32 tiles per bh
  int t0 = (blockIdx.x & 31) * 64;
  __shared__ float sT[64][65];       // [d][t], padded
  int tid = threadIdx.x;
  int tr = tid >> 2;                 // t within tile, 0..63
  int dc = (tid & 3) * 16;           // d start
  const float* vp = V + ((size_t)bh * NS + t0 + tr) * ND + dc;
  #pragma unroll
  for (int j = 0; j < 16; j += 4) {
    float4 v = *(const float4*)(vp + j);
    sT[dc + j + 0][tr] = v.x;
    sT[dc + j + 1][tr] = v.y;
    sT[dc + j + 2][tr] = v.z;
    sT[dc + j + 3][tr] = v.w;
  }
  __syncthreads();
  int dr = tid >> 2;                 // d row
  int tc = (tid & 3) * 16;           // t start
  unsigned short* op = Vt + ((size_t)bh * ND + dr) * NS + t0 + tc;
  #pragma unroll
  for (int j = 0; j < 16; ++j) op[j] = f32_to_bf16(sT[dr][tc + j]);
}

// ---------------------------------------------------------------------------
// Main: per (bh, 64-query tile) block, 4 waves; wave w owns query rows
// [w*16, w*16+16). Loop over 32 key tiles of 64:
//   scores = qn @ kn^T (MFMA bf16) -> transform (clip/acos/^8/key-mask, fp32)
//   -> W bf16 via LDS (C-layout -> A-layout) -> X += W @ V (MFMA bf16).
// Epilogue: query mask, l2norm (16-lane shuffle), + depthwise conv3 (fp32 V).
// ---------------------------------------------------------------------------
__global__ __launch_bounds__(256) void yoso_main(
    const unsigned short* __restrict__ qn, const unsigned short* __restrict__ kn,
    const unsigned short* __restrict__ Vt, const float* __restrict__ V,
    const float* __restrict__ mask, const float* __restrict__ conv_w,
    float* __restrict__ out) {
  int bh = blockIdx.x >> 5;              // 32 q-tiles per bh
  int b  = bh / NH;
  int h  = bh % NH;
  int s0 = (blockIdx.x & 31) * 64;

  __shared__ unsigned short sQ[64 * LDK];
  __shared__ unsigned short sK[64 * LDK];
  __shared__ unsigned short sV[64 * LDK];   // V tile transposed: [d][t]
  __shared__ unsigned short sW[64 * LDK];   // transformed scores, [q][t]

  int tid  = threadIdx.x;
  int wv   = tid >> 6;       // wave 0..3
  int lane = tid & 63;
  int lq   = lane & 15;      // n/m index within 16
  int quad = lane >> 4;      // 0..3

  // Load qn tile (rows s0..s0+63, 64 bf16 each) once.
  {
    const unsigned short* qp = qn + ((size_t)bh * NS + s0) * ND;
    #pragma unroll
    for (int p = 0; p < 2; ++p) {
      int r = p * 32 + (tid >> 3);
      int c = (tid & 7) * 8;
      *(uint4*)(&sQ[r * LDK + c]) = *(const uint4*)(qp + r * ND + c);
    }
  }

  float w0 = conv_w[h * 3 + 0], w1 = conv_w[h * 3 + 1], w2 = conv_w[h * 3 + 2];

  floatx4 acc[4];
  #pragma unroll
  for (int i = 0; i < 4; ++i) acc[i] = (floatx4){0.f, 0.f, 0.f, 0.f};

  const unsigned short* kbase = kn + (size_t)bh * NS * ND;
  const unsigned short* vtb   = Vt + (size_t)bh * ND * NS;
  const float inv_pi = 0.31830988618367f;

  for (int kt = 0; kt < NS / 64; ++kt) {
    int t0 = kt * 64;
    __syncthreads();   // all waves done reading previous sK/sV
    #pragma unroll
    for (int p = 0; p < 2; ++p) {
      int r = p * 32 + (tid >> 3);
      int c = (tid & 7) * 8;
      *(uint4*)(&sK[r * LDK + c]) = *(const uint4*)(kbase + (size_t)(t0 + r) * ND + c);
      *(uint4*)(&sV[r * LDK + c]) = *(const uint4*)(vtb + (size_t)r * NS + t0 + c);
    }
    __syncthreads();

    // scores: rows q = wv*16+m, cols t = 0..63
    floatx4 sc[4];
    #pragma unroll
    for (int i = 0; i < 4; ++i) sc[i] = (floatx4){0.f, 0.f, 0.f, 0.f};
    #pragma unroll
    for (int kk = 0; kk < 2; ++kk) {
      short8 a = *(const short8*)(&sQ[(wv * 16 + lq) * LDK + kk * 32 + quad * 8]);
      #pragma unroll
      for (int fn = 0; fn < 4; ++fn) {
        short8 bf = *(const short8*)(&sK[(fn * 16 + lq) * LDK + kk * 32 + quad * 8]);
        sc[fn] = __builtin_amdgcn_mfma_f32_16x16x32_bf16(a, bf, sc[fn], 0, 0, 0);
      }
    }

    // transform + key mask, C-layout (q = quad*4+r, t = fn*16+lq) -> sW[q][t]
    #pragma unroll
    for (int fn = 0; fn < 4; ++fn) {
      float km = mask[b * NS + t0 + fn * 16 + lq];
      #pragma unroll
      for (int r = 0; r < 4; ++r) {
        float d = sc[fn][r];
        d = fminf(fmaxf(d, -1.0f), 1.0f);
        float f = 1.0f - acosf(d) * inv_pi;
        float f2 = f * f;
        float f4 = f2 * f2;
        float w = f4 * f4 * km;
        sW[(wv * 16 + quad * 4 + r) * LDK + fn * 16 + lq] = f32_to_bf16(w);
      }
    }
    // Wave reads back only its own rows of sW -> no cross-wave barrier needed.

    // X += W @ V : A = sW rows (q, k=t), B = sV rows (n=d, k=t)
    #pragma unroll
    for (int kk = 0; kk < 2; ++kk) {
      short8 a = *(const short8*)(&sW[(wv * 16 + lq) * LDK + kk * 32 + quad * 8]);
      #pragma unroll
      for (int fn = 0; fn < 4; ++fn) {
        short8 bf = *(const short8*)(&sV[(fn * 16 + lq) * LDK + kk * 32 + quad * 8]);
        acc[fn] = __builtin_amdgcn_mfma_f32_16x16x32_bf16(a, bf, acc[fn], 0, 0, 0);
      }
    }
  }

  // Epilogue: query mask, l2norm over D (row lives in the 16 lanes of this quad
  // group, 4 values per lane), then + depthwise conv3 from exact fp32 V.
  const float* vb = V + (size_t)bh * NS * ND;
  #pragma unroll
  for (int r = 0; r < 4; ++r) {
    int q = quad * 4 + r;
    int s = s0 + wv * 16 + q;
    float qm = mask[b * NS + s];
    float xv[4];
    float ss = 0.f;
    #pragma unroll
    for (int fn = 0; fn < 4; ++fn) {
      float v = acc[fn][r] * qm;
      xv[fn] = v;
      ss += v * v;
    }
    ss += __shfl_xor(ss, 1, 64);
    ss += __shfl_xor(ss, 2, 64);
    ss += __shfl_xor(ss, 4, 64);
    ss += __shfl_xor(ss, 8, 64);
    float rn = 1.0f / fmaxf(sqrtf(ss), 1e-12f);
    #pragma unroll
    for (int fn = 0; fn < 4; ++fn) {
      int d = fn * 16 + lq;
      const float* vcol = vb + d;
      float cv = w1 * vcol[(size_t)s * ND] * mask[b * NS + s];
      if (s > 0)      cv += w0 * vcol[(size_t)(s - 1) * ND] * mask[b * NS + s - 1];
      if (s < NS - 1) cv += w2 * vcol[(size_t)(s + 1) * ND] * mask[b * NS + s + 1];
      out[((size_t)bh * NS + s) * ND + d] = xv[fn] * rn + cv;
    }
  }
}

// ---------------------------------------------------------------------------
extern "C" void kernel_launch(void* const* d_in, const int* in_sizes, int n_in,
                              void* d_out, int out_size, void* d_ws, size_t ws_size,
                              hipStream_t stream) {
  const float* Q      = (const float*)d_in[0];
  const float* K      = (const float*)d_in[1];
  const float* V      = (const float*)d_in[2];
  const float* mask   = (const float*)d_in[3];
  const float* conv_w = (const float*)d_in[4];
  float* out = (float*)d_out;

  // Workspace layout (bf16): qn | kn | Vt, each NBH*NS*ND elems.
  const size_t seg = (size_t)NBH * NS * ND * sizeof(unsigned short);  // 6.29 MB
  unsigned short* qn = (unsigned short*)d_ws;
  unsigned short* kn = (unsigned short*)((char*)d_ws + seg);
  unsigned short* Vt = (unsigned short*)((char*)d_ws + 2 * seg);

  // 2*NBH*NS rows, 4 rows (waves) per block
  prep_qk<<<(2 * NBH * NS) / 4, 256, 0, stream>>>(Q, K, qn, kn);
  prep_v<<<NBH * (NS / 64), 256, 0, stream>>>(V, Vt);
  yoso_main<<<NBH * (NS / 64), 256, 0, stream>>>(qn, kn, Vt, V, mask, conv_w, out);
}